// Round 1
// baseline (386.033 us; speedup 1.0000x reference)
//
#include <hip/hip_runtime.h>
#include <math.h>
#include <string.h>

#define CDIM 64
#define DEG  11   // polynomial degree; 12 coefficients = 4 Horner blocks of 3

struct Coefs { float a[12]; float cc; float inv_h; };

// C_tile[i0..i0+3][j0..j0+3] += sum_k A[k][i]*B[k][j]
// A,B symmetric (all operands are polynomials of the same M), so this equals (A*B)[i][j].
// Both operands are read ROW-wise -> conflict-free ds_read_b128.
__device__ __forceinline__ void matmul_acc(const float* __restrict__ A,
                                           const float* __restrict__ B,
                                           float acc[4][4], int i0, int j0) {
#pragma unroll 4
    for (int k = 0; k < CDIM; ++k) {
        const float4 av = *reinterpret_cast<const float4*>(A + k * CDIM + i0);
        const float4 bv = *reinterpret_cast<const float4*>(B + k * CDIM + j0);
        const float a[4] = {av.x, av.y, av.z, av.w};
        const float b[4] = {bv.x, bv.y, bv.z, bv.w};
#pragma unroll
        for (int di = 0; di < 4; ++di)
#pragma unroll
            for (int dj = 0; dj < 4; ++dj)
                acc[di][dj] = fmaf(a[di], b[dj], acc[di][dj]);
    }
}

__global__ void __launch_bounds__(256, 2)
logm_kernel(const float* __restrict__ X, float* __restrict__ Y, Coefs cf) {
    __shared__ float M1[CDIM * CDIM];
    __shared__ float M2[CDIM * CDIM];
    __shared__ float M3[CDIM * CDIM];
    __shared__ float P [CDIM * CDIM];

    const int tid = threadIdx.x;
    const int m   = blockIdx.x;

    const float* __restrict__ Xm = X + (size_t)m * (CDIM * CDIM);
    float* __restrict__ Ym       = Y + (size_t)m * (CDIM * CDIM);

    // ---- load & form M1 = (X - cc*I) * inv_h (coalesced float4) ----
    for (int base = tid * 4; base < CDIM * CDIM; base += 256 * 4) {
        float4 v = *reinterpret_cast<const float4*>(Xm + base);
        const int i = base >> 6;   // row
        const int j = base & 63;   // first col of this float4
        const int d = i - j;
        if (d >= 0 && d < 4) (&v.x)[d] -= cf.cc;  // diagonal shift
        v.x *= cf.inv_h; v.y *= cf.inv_h; v.z *= cf.inv_h; v.w *= cf.inv_h;
        *reinterpret_cast<float4*>(M1 + base) = v;
    }
    __syncthreads();

    const int i0 = (tid >> 4) * 4;
    const int j0 = (tid & 15) * 4;
    float acc[4][4];

    // ---- M2 = M1*M1 ----
#pragma unroll
    for (int di = 0; di < 4; ++di)
#pragma unroll
        for (int dj = 0; dj < 4; ++dj) acc[di][dj] = 0.0f;
    matmul_acc(M1, M1, acc, i0, j0);
#pragma unroll
    for (int di = 0; di < 4; ++di)
        *reinterpret_cast<float4*>(M2 + (i0 + di) * CDIM + j0) =
            make_float4(acc[di][0], acc[di][1], acc[di][2], acc[di][3]);
    __syncthreads();

    // ---- M3 = M2*M1, and P = B3 = a[9] I + a[10] M1 + a[11] M2 ----
#pragma unroll
    for (int di = 0; di < 4; ++di)
#pragma unroll
        for (int dj = 0; dj < 4; ++dj) acc[di][dj] = 0.0f;
    matmul_acc(M2, M1, acc, i0, j0);
#pragma unroll
    for (int di = 0; di < 4; ++di) {
        *reinterpret_cast<float4*>(M3 + (i0 + di) * CDIM + j0) =
            make_float4(acc[di][0], acc[di][1], acc[di][2], acc[di][3]);
#pragma unroll
        for (int dj = 0; dj < 4; ++dj) {
            const int idx = (i0 + di) * CDIM + (j0 + dj);
            float e = cf.a[11] * M2[idx] + cf.a[10] * M1[idx];
            if (i0 + di == j0 + dj) e += cf.a[9];
            P[idx] = e;
        }
    }
    __syncthreads();

    // ---- Horner over blocks: P <- P*M3 + (a[3r+2] M2 + a[3r+1] M1 + a[3r] I) ----
    for (int r = 2; r >= 1; --r) {
#pragma unroll
        for (int di = 0; di < 4; ++di)
#pragma unroll
            for (int dj = 0; dj < 4; ++dj) acc[di][dj] = 0.0f;
        matmul_acc(P, M3, acc, i0, j0);
        __syncthreads();  // all reads of P complete before overwrite
        const float b2 = cf.a[3 * r + 2], b1 = cf.a[3 * r + 1], b0 = cf.a[3 * r];
#pragma unroll
        for (int di = 0; di < 4; ++di)
#pragma unroll
            for (int dj = 0; dj < 4; ++dj) {
                const int idx = (i0 + di) * CDIM + (j0 + dj);
                float e = acc[di][dj] + b2 * M2[idx] + b1 * M1[idx];
                if (i0 + di == j0 + dj) e += b0;
                P[idx] = e;
            }
        __syncthreads();
    }

    // ---- final block r=0: write straight to global ----
#pragma unroll
    for (int di = 0; di < 4; ++di)
#pragma unroll
        for (int dj = 0; dj < 4; ++dj) acc[di][dj] = 0.0f;
    matmul_acc(P, M3, acc, i0, j0);
    const float b2 = cf.a[2], b1 = cf.a[1], b0 = cf.a[0];
#pragma unroll
    for (int di = 0; di < 4; ++di) {
        float o[4];
#pragma unroll
        for (int dj = 0; dj < 4; ++dj) {
            const int idx = (i0 + di) * CDIM + (j0 + dj);
            o[dj] = acc[di][dj] + b2 * M2[idx] + b1 * M1[idx];
            if (i0 + di == j0 + dj) o[dj] += b0;
        }
        *reinterpret_cast<float4*>(Ym + (i0 + di) * CDIM + j0) =
            make_float4(o[0], o[1], o[2], o[3]);
    }
}

extern "C" void kernel_launch(void* const* d_in, const int* in_sizes, int n_in,
                              void* d_out, int out_size, void* d_ws, size_t ws_size,
                              hipStream_t stream) {
    const float* X = (const float*)d_in[0];
    float* Y = (float*)d_out;
    const int nmat = in_sizes[0] / (CDIM * CDIM);

    // ---- host-side: Chebyshev coefficients of log on [lo,hi], converted to
    // monomial basis in t = (x-cc)/hh. Analytic: log(cc+hh*t) = log(A) - 2*sum z^k/k T_k(t)
    Coefs cf;
    {
        const double lo = 1.0, hi = 7.5;
        const double cc = 0.5 * (lo + hi), hh = 0.5 * (hi - lo);
        const double s  = sqrt(cc * cc - hh * hh);
        const double z  = (-cc + s) / hh;          // |z| < 1
        const double A  = 0.5 * (cc + s);
        double cheb[DEG + 1];
        cheb[0] = log(A);
        double zp = 1.0;
        for (int k = 1; k <= DEG; ++k) { zp *= z; cheb[k] = -2.0 * zp / (double)k; }
        // Chebyshev -> monomial via T_k recurrence (double precision, deg<=11: exact enough)
        double mono[DEG + 1], Tprev[DEG + 1], Tcur[DEG + 1];
        memset(mono, 0, sizeof(mono));
        memset(Tprev, 0, sizeof(Tprev));
        memset(Tcur, 0, sizeof(Tcur));
        Tprev[0] = 1.0; mono[0] += cheb[0] * 1.0;   // T0
        Tcur[1]  = 1.0; mono[1] += cheb[1] * 1.0;   // T1
        for (int k = 2; k <= DEG; ++k) {
            double Tn[DEG + 1];
            memset(Tn, 0, sizeof(Tn));
            for (int j = 0; j <= k; ++j) {
                double v = -Tprev[j];
                if (j > 0) v += 2.0 * Tcur[j - 1];
                Tn[j] = v;
            }
            for (int j = 0; j <= k; ++j) mono[j] += cheb[k] * Tn[j];
            for (int j = 0; j <= DEG; ++j) { Tprev[j] = Tcur[j]; Tcur[j] = Tn[j]; }
        }
        for (int i = 0; i < 12; ++i) cf.a[i] = (float)mono[i];
        cf.cc = (float)cc; cf.inv_h = (float)(1.0 / hh);
    }

    dim3 grid(nmat), block(256);
    hipLaunchKernelGGL(logm_kernel, grid, block, 0, stream, X, Y, cf);
}

// Round 2
// 210.265 us; speedup vs baseline: 1.8359x; 1.8359x over previous
//
#include <hip/hip_runtime.h>
#include <math.h>
#include <string.h>

#define CDIM 64
#define LDSW 72   // padded LDS row stride in bf16 elems (144 B = 36 words: breaks 32-bank aliasing, keeps 16 B align)
#define DEG  8    // Chebyshev tail ~4.2e-4 on [1,7.5]; PS s=3 -> 4 matmuls

struct Coefs { float a[DEG + 1]; float cc; float inv_h; };

typedef __attribute__((ext_vector_type(8)))  short          short8;    // 8 bf16 = 4 VGPRs (MFMA A/B frag)
typedef __attribute__((ext_vector_type(16))) float          floatx16;  // MFMA C/D
typedef __attribute__((ext_vector_type(4)))  unsigned short ushort4v;

__device__ __forceinline__ unsigned short bf16_rne(float x) {
  unsigned u = __builtin_bit_cast(unsigned, x);
  u += 0x7FFFu + ((u >> 16) & 1u);          // round-to-nearest-even
  return (unsigned short)(u >> 16);
}
__device__ __forceinline__ float bf16_f(unsigned short h) {
  unsigned u = ((unsigned)h) << 16;
  return __builtin_bit_cast(float, u);
}
// write x as (hi,lo) bf16 pair
__device__ __forceinline__ void wb(unsigned short* __restrict__ Dh,
                                   unsigned short* __restrict__ Dl,
                                   float x, int idx) {
  unsigned short h = bf16_rne(x);
  Dh[idx] = h;
  Dl[idx] = bf16_rne(x - bf16_f(h));
}

// 32x32 tile of S*T for symmetric S,T stored row-major (hi/lo bf16) in LDS.
// B-operand B[k][n] read as row n via symmetry -> both frags are ds_read_b128.
// 3-MFMA compensated product: AhBh + AhBl + AlBh (AlBl ~ 2^-18, dropped).
__device__ __forceinline__ floatx16 mm64(const unsigned short* __restrict__ Sh,
                                         const unsigned short* __restrict__ Sl,
                                         const unsigned short* __restrict__ Th,
                                         const unsigned short* __restrict__ Tl,
                                         int arow, int brow, int ko) {
  floatx16 acc;
#pragma unroll
  for (int i = 0; i < 16; ++i) acc[i] = 0.0f;
#pragma unroll
  for (int kk = 0; kk < 4; ++kk) {
    const int k0 = kk * 16 + ko;
    short8 ah = *(const short8*)(Sh + arow * LDSW + k0);
    short8 al = *(const short8*)(Sl + arow * LDSW + k0);
    short8 bh = *(const short8*)(Th + brow * LDSW + k0);
    short8 bl = *(const short8*)(Tl + brow * LDSW + k0);
    acc = __builtin_amdgcn_mfma_f32_32x32x16_bf16(ah, bh, acc, 0, 0, 0);
    acc = __builtin_amdgcn_mfma_f32_32x32x16_bf16(ah, bl, acc, 0, 0, 0);
    acc = __builtin_amdgcn_mfma_f32_32x32x16_bf16(al, bh, acc, 0, 0, 0);
  }
  return acc;
}

__global__ void __launch_bounds__(256, 2)
logm_kernel(const float* __restrict__ X, float* __restrict__ Y, Coefs cf) {
  // 3 ping-pong buffer pairs: A = M1 then P0, B = M2 then P1, C = M3.  55.3 KB -> 2 blocks/CU.
  __shared__ __align__(16) unsigned short Ah[CDIM * LDSW], Al[CDIM * LDSW];
  __shared__ __align__(16) unsigned short Bh[CDIM * LDSW], Bl[CDIM * LDSW];
  __shared__ __align__(16) unsigned short Ch[CDIM * LDSW], Cl[CDIM * LDSW];

  const int tid  = threadIdx.x;
  const int lane = tid & 63;
  const int w    = tid >> 6;          // wave 0..3
  const int m    = blockIdx.x;

  const float* __restrict__ Xm = X + (size_t)m * (CDIM * CDIM);
  float* __restrict__ Ym       = Y + (size_t)m * (CDIM * CDIM);

  // ---- stage M1 = (X - cc I) * inv_h into A as hi/lo bf16 (coalesced float4 loads) ----
#pragma unroll
  for (int it = 0; it < 4; ++it) {
    const int base = tid * 4 + it * 1024;
    float4 v = *(const float4*)(Xm + base);
    const int row = base >> 6, colb = base & 63;
    float e[4] = {v.x, v.y, v.z, v.w};
    const int d = row - colb;
    if (d >= 0 && d < 4) e[d] -= cf.cc;
    ushort4v hs, ls;
#pragma unroll
    for (int j = 0; j < 4; ++j) {
      const float t = e[j] * cf.inv_h;
      const unsigned short h = bf16_rne(t);
      hs[j] = h;
      ls[j] = bf16_rne(t - bf16_f(h));
    }
    *(ushort4v*)(&Ah[row * LDSW + colb]) = hs;
    *(ushort4v*)(&Al[row * LDSW + colb]) = ls;
  }

  // ---- per-wave 32x32 tile coords ----
  const int R    = (w >> 1) * 32;          // tile row base
  const int Cc   = (w & 1) * 32;           // tile col base
  const int l31  = lane & 31;
  const int half = lane >> 5;
  const int arow = R + l31;                // A-frag row (m index)
  const int brow = Cc + l31;               // B-frag row (n index, via symmetry)
  const int ko   = half * 8;
  const int col  = Cc + l31;               // C-layout col
  int rows[16];                            // C-layout rows (verified m74/m101 mapping)
#pragma unroll
  for (int r = 0; r < 16; ++r) rows[r] = R + (r & 3) + 8 * (r >> 2) + 4 * half;

  // ---- M1 at this lane's C positions, exact fp32, straight from global (L1/L2 hot) ----
  float rM1[16];
#pragma unroll
  for (int r = 0; r < 16; ++r) {
    float x = Xm[rows[r] * CDIM + col];
    if (rows[r] == col) x -= cf.cc;
    rM1[r] = x * cf.inv_h;
  }
  __syncthreads();

  // ---- M2 = M1*M1 ; keep in regs, write hi/lo to B ----
  floatx16 accM2 = mm64(Ah, Al, Ah, Al, arow, brow, ko);
  float rM2[16];
#pragma unroll
  for (int r = 0; r < 16; ++r) {
    rM2[r] = accM2[r];
    wb(Bh, Bl, rM2[r], rows[r] * LDSW + col);
  }
  __syncthreads();

  // ---- M3 = M2*M1 -> C ; P0 = a6 I + a7 M1 + a8 M2 (registers) -> A ----
  floatx16 accM3 = mm64(Bh, Bl, Ah, Al, arow, brow, ko);
  __syncthreads();   // all waves done READING A (M1) before we overwrite it with P0
#pragma unroll
  for (int r = 0; r < 16; ++r) {
    const int idx = rows[r] * LDSW + col;
    wb(Ch, Cl, accM3[r], idx);
    float p = cf.a[7] * rM1[r] + cf.a[8] * rM2[r];
    if (rows[r] == col) p += cf.a[6];
    wb(Ah, Al, p, idx);
  }
  __syncthreads();

  // ---- P1 = P0*M3 + (a3 I + a4 M1 + a5 M2) -> B  (B's last readers finished pre-barrier) ----
  floatx16 accP = mm64(Ah, Al, Ch, Cl, arow, brow, ko);
#pragma unroll
  for (int r = 0; r < 16; ++r) {
    float p = accP[r] + cf.a[4] * rM1[r] + cf.a[5] * rM2[r];
    if (rows[r] == col) p += cf.a[3];
    wb(Bh, Bl, p, rows[r] * LDSW + col);
  }
  __syncthreads();

  // ---- out = P1*M3 + (a0 I + a1 M1 + a2 M2) -> global (rows of 32 consecutive cols: coalesced 128B) ----
  floatx16 accF = mm64(Bh, Bl, Ch, Cl, arow, brow, ko);
#pragma unroll
  for (int r = 0; r < 16; ++r) {
    float p = accF[r] + cf.a[1] * rM1[r] + cf.a[2] * rM2[r];
    if (rows[r] == col) p += cf.a[0];
    Ym[rows[r] * CDIM + col] = p;
  }
}

extern "C" void kernel_launch(void* const* d_in, const int* in_sizes, int n_in,
                              void* d_out, int out_size, void* d_ws, size_t ws_size,
                              hipStream_t stream) {
  const float* X = (const float*)d_in[0];
  float* Y = (float*)d_out;
  const int nmat = in_sizes[0] / (CDIM * CDIM);

  // Chebyshev coefficients of log on [lo,hi] -> monomial basis in t=(x-cc)/hh.
  // Analytic: log(cc+hh*t) = log(A) - 2*sum_k z^k/k T_k(t),  z=(-cc+sqrt(cc^2-hh^2))/hh
  Coefs cf;
  {
    const double lo = 1.0, hi = 7.5;
    const double cc = 0.5 * (lo + hi), hh = 0.5 * (hi - lo);
    const double s  = sqrt(cc * cc - hh * hh);
    const double z  = (-cc + s) / hh;
    const double A  = 0.5 * (cc + s);
    double cheb[DEG + 1];
    cheb[0] = log(A);
    double zp = 1.0;
    for (int k = 1; k <= DEG; ++k) { zp *= z; cheb[k] = -2.0 * zp / (double)k; }
    double mono[DEG + 1], Tprev[DEG + 1], Tcur[DEG + 1];
    memset(mono, 0, sizeof(mono));
    memset(Tprev, 0, sizeof(Tprev));
    memset(Tcur, 0, sizeof(Tcur));
    Tprev[0] = 1.0; mono[0] += cheb[0];
    Tcur[1]  = 1.0; mono[1] += cheb[1];
    for (int k = 2; k <= DEG; ++k) {
      double Tn[DEG + 1];
      memset(Tn, 0, sizeof(Tn));
      for (int j = 0; j <= k; ++j) {
        double v = -Tprev[j];
        if (j > 0) v += 2.0 * Tcur[j - 1];
        Tn[j] = v;
      }
      for (int j = 0; j <= k; ++j) mono[j] += cheb[k] * Tn[j];
      for (int j = 0; j <= DEG; ++j) { Tprev[j] = Tcur[j]; Tcur[j] = Tn[j]; }
    }
    for (int i = 0; i <= DEG; ++i) cf.a[i] = (float)mono[i];
    cf.cc = (float)cc; cf.inv_h = (float)(1.0 / hh);
  }

  dim3 grid(nmat), block(256);
  hipLaunchKernelGGL(logm_kernel, grid, block, 0, stream, X, Y, cf);
}

// Round 3
// 195.241 us; speedup vs baseline: 1.9772x; 1.0769x over previous
//
#include <hip/hip_runtime.h>
#include <math.h>
#include <string.h>

#define CDIM 64
#define LDSW 72   // padded LDS row stride in bf16 elems (144 B): 16B-aligned rows, measured 0 bank conflicts
#define DEG  8    // Chebyshev tail ~4.2e-4 on [1,7.5]; Paterson-Stockmeyer s=3 -> 4 matmuls

struct Coefs { float a[DEG + 1]; float cc; float inv_h; };

typedef __attribute__((ext_vector_type(8)))  short short8;    // 8 bf16 = 4 VGPRs (MFMA A/B frag)
typedef __attribute__((ext_vector_type(16))) float floatx16;  // MFMA C/D

// pack hi16(a) into low half, hi16(b) into high half: one v_perm_b32
__device__ __forceinline__ unsigned pack2(unsigned a, unsigned b) {
  return __builtin_amdgcn_perm(b, a, 0x07060302u);
}

// Truncation hi/lo split of 4 fp32 -> 4 consecutive bf16 slots in Dh/Dl, one b64 store each.
// hi = x with low16 zeroed (error <= 2^-8 rel); lo = bf16_trunc(x - hi) (residual ~2^-16 rel).
__device__ __forceinline__ void store4(unsigned short* __restrict__ Dh,
                                       unsigned short* __restrict__ Dl,
                                       int idx, const float t[4]) {
  unsigned u[4], lb[4];
#pragma unroll
  for (int j = 0; j < 4; ++j) {
    u[j] = __builtin_bit_cast(unsigned, t[j]);
    const unsigned hf = u[j] & 0xFFFF0000u;
    const float lo = t[j] - __builtin_bit_cast(float, hf);
    lb[j] = __builtin_bit_cast(unsigned, lo);
  }
  unsigned long long hv = ((unsigned long long)pack2(u[2], u[3]) << 32) | pack2(u[0], u[1]);
  unsigned long long lv = ((unsigned long long)pack2(lb[2], lb[3]) << 32) | pack2(lb[0], lb[1]);
  *(unsigned long long*)(Dh + idx) = hv;
  *(unsigned long long*)(Dl + idx) = lv;
}

struct Frags { short8 h[4]; short8 l[4]; };  // 4 K-slabs of hi+lo A/B fragments (32 VGPRs)

__device__ __forceinline__ void load_frags(const unsigned short* __restrict__ Ph,
                                           const unsigned short* __restrict__ Pl,
                                           int row, int ko, Frags* f) {
#pragma unroll
  for (int kk = 0; kk < 4; ++kk) {
    f->h[kk] = *(const short8*)(Ph + row * LDSW + kk * 16 + ko);
    f->l[kk] = *(const short8*)(Pl + row * LDSW + kk * 16 + ko);
  }
}

// 32x32 tile of S*T (symmetric operands), 3-MFMA compensated product with
// 3 independent accumulator chains (ILP), combined at the end.
__device__ __forceinline__ floatx16 mm_frags(const Frags& a, const Frags& b) {
  floatx16 c1, c2, c3;
#pragma unroll
  for (int i = 0; i < 16; ++i) { c1[i] = 0.0f; c2[i] = 0.0f; c3[i] = 0.0f; }
#pragma unroll
  for (int kk = 0; kk < 4; ++kk) {
    c1 = __builtin_amdgcn_mfma_f32_32x32x16_bf16(a.h[kk], b.h[kk], c1, 0, 0, 0);
    c2 = __builtin_amdgcn_mfma_f32_32x32x16_bf16(a.h[kk], b.l[kk], c2, 0, 0, 0);
    c3 = __builtin_amdgcn_mfma_f32_32x32x16_bf16(a.l[kk], b.h[kk], c3, 0, 0, 0);
  }
#pragma unroll
  for (int i = 0; i < 16; ++i) c1[i] += c2[i] + c3[i];
  return c1;
}

__global__ void __launch_bounds__(256, 2)
logm_kernel(const float* __restrict__ X, float* __restrict__ Y, Coefs cf) {
  // Buffers: A = M1 then P0, B = M2 then P1, C = M3.  6 x 9216 B = 55.3 KB -> 2 blocks/CU.
  __shared__ __align__(16) unsigned short Ah[CDIM * LDSW], Al[CDIM * LDSW];
  __shared__ __align__(16) unsigned short Bh[CDIM * LDSW], Bl[CDIM * LDSW];
  __shared__ __align__(16) unsigned short Ch[CDIM * LDSW], Cl[CDIM * LDSW];

  const int tid  = threadIdx.x;
  const int lane = tid & 63;
  const int w    = tid >> 6;
  const int m    = blockIdx.x;

  const float* __restrict__ Xm = X + (size_t)m * (CDIM * CDIM);
  float* __restrict__ Ym       = Y + (size_t)m * (CDIM * CDIM);

  const int R    = (w >> 1) * 32;
  const int Cc   = (w & 1) * 32;
  const int l31  = lane & 31;
  const int half = lane >> 5;
  const int arow = R + l31;
  const int brow = Cc + l31;
  const int ko   = half * 8;
  const int col  = Cc + l31;
  int rows[16];  // C/D layout: row = (r&3) + 8*(r>>2) + 4*half  [verified m74/m101]
#pragma unroll
  for (int r = 0; r < 16; ++r) rows[r] = R + (r & 3) + 8 * (r >> 2) + 4 * half;

  // ---- stage: load X once in C-layout (coalesced dwords), keep rM1 in regs,
  //      write M1 hi/lo to A TRANSPOSED (consecutive rows -> packed b64; X symmetric) ----
  float rM1[16];
#pragma unroll
  for (int g = 0; g < 4; ++g) {
    float t[4];
#pragma unroll
    for (int j = 0; j < 4; ++j) {
      const int r = 4 * g + j;
      float x = Xm[rows[r] * CDIM + col];
      if (rows[r] == col) x -= cf.cc;
      t[j] = x * cf.inv_h;
      rM1[r] = t[j];
    }
    store4(Ah, Al, col * LDSW + rows[4 * g], t);
  }
  __syncthreads();

  // ---- mm1: M2 = M1*M1 ----
  Frags fa, fb;
  load_frags(Ah, Al, arow, ko, &fa);
  if (R == Cc) fb = fa; else load_frags(Ah, Al, brow, ko, &fb);  // wave-uniform
  floatx16 accM2 = mm_frags(fa, fb);
  float rM2[16];
#pragma unroll
  for (int g = 0; g < 4; ++g) {
    float t[4];
#pragma unroll
    for (int j = 0; j < 4; ++j) { const int r = 4 * g + j; rM2[r] = accM2[r]; t[j] = accM2[r]; }
    store4(Bh, Bl, col * LDSW + rows[4 * g], t);
  }
  __syncthreads();

  // ---- mm2: M3 = M2*M1 (T-frag of M1 cached in fb) ----
  Frags fa2;
  load_frags(Bh, Bl, arow, ko, &fa2);
  floatx16 accM3 = mm_frags(fa2, fb);
  // All waves' reads of A finished before the previous barrier -> safe to overwrite A now.
  // M3 -> C,  P0 = a6 I + a7 M1 + a8 M2 -> A   (register epilogue)
#pragma unroll
  for (int g = 0; g < 4; ++g) {
    float tc[4], tp[4];
#pragma unroll
    for (int j = 0; j < 4; ++j) {
      const int r = 4 * g + j;
      tc[j] = accM3[r];
      float p = cf.a[7] * rM1[r] + cf.a[8] * rM2[r];
      if (rows[r] == col) p += cf.a[6];
      tp[j] = p;
    }
    const int idx = col * LDSW + rows[4 * g];
    store4(Ch, Cl, idx, tc);
    store4(Ah, Al, idx, tp);
  }
  __syncthreads();

  // ---- mm3: P1 = P0*M3 + (a3 I + a4 M1 + a5 M2) ----
  Frags fp, fm3;
  load_frags(Ah, Al, arow, ko, &fp);
  load_frags(Ch, Cl, brow, ko, &fm3);   // cached for mm4 too
  floatx16 accP = mm_frags(fp, fm3);
  // B's last readers finished before previous barrier -> safe to overwrite.
#pragma unroll
  for (int g = 0; g < 4; ++g) {
    float t[4];
#pragma unroll
    for (int j = 0; j < 4; ++j) {
      const int r = 4 * g + j;
      float p = accP[r] + cf.a[4] * rM1[r] + cf.a[5] * rM2[r];
      if (rows[r] == col) p += cf.a[3];
      t[j] = p;
    }
    store4(Bh, Bl, col * LDSW + rows[4 * g], t);
  }
  __syncthreads();

  // ---- mm4: out = P1*M3 + (a0 I + a1 M1 + a2 M2) -> global ----
  Frags fp1;
  load_frags(Bh, Bl, arow, ko, &fp1);
  floatx16 accF = mm_frags(fp1, fm3);
#pragma unroll
  for (int r = 0; r < 16; ++r) {
    float p = accF[r] + cf.a[1] * rM1[r] + cf.a[2] * rM2[r];
    if (rows[r] == col) p += cf.a[0];
    Ym[rows[r] * CDIM + col] = p;
  }
}

extern "C" void kernel_launch(void* const* d_in, const int* in_sizes, int n_in,
                              void* d_out, int out_size, void* d_ws, size_t ws_size,
                              hipStream_t stream) {
  const float* X = (const float*)d_in[0];
  float* Y = (float*)d_out;
  const int nmat = in_sizes[0] / (CDIM * CDIM);

  // Chebyshev coefficients of log on [lo,hi] -> monomial basis in t=(x-cc)/hh.
  // Analytic: log(cc+hh*t) = log(A) - 2*sum_k z^k/k T_k(t),  z=(-cc+sqrt(cc^2-hh^2))/hh
  Coefs cf;
  {
    const double lo = 1.0, hi = 7.5;
    const double cc = 0.5 * (lo + hi), hh = 0.5 * (hi - lo);
    const double s  = sqrt(cc * cc - hh * hh);
    const double z  = (-cc + s) / hh;
    const double A  = 0.5 * (cc + s);
    double cheb[DEG + 1];
    cheb[0] = log(A);
    double zp = 1.0;
    for (int k = 1; k <= DEG; ++k) { zp *= z; cheb[k] = -2.0 * zp / (double)k; }
    double mono[DEG + 1], Tprev[DEG + 1], Tcur[DEG + 1];
    memset(mono, 0, sizeof(mono));
    memset(Tprev, 0, sizeof(Tprev));
    memset(Tcur, 0, sizeof(Tcur));
    Tprev[0] = 1.0; mono[0] += cheb[0];
    Tcur[1]  = 1.0; mono[1] += cheb[1];
    for (int k = 2; k <= DEG; ++k) {
      double Tn[DEG + 1];
      memset(Tn, 0, sizeof(Tn));
      for (int j = 0; j <= k; ++j) {
        double v = -Tprev[j];
        if (j > 0) v += 2.0 * Tcur[j - 1];
        Tn[j] = v;
      }
      for (int j = 0; j <= k; ++j) mono[j] += cheb[k] * Tn[j];
      for (int j = 0; j <= DEG; ++j) { Tprev[j] = Tcur[j]; Tcur[j] = Tn[j]; }
    }
    for (int i = 0; i <= DEG; ++i) cf.a[i] = (float)mono[i];
    cf.cc = (float)cc; cf.inv_h = (float)(1.0 / hh);
  }

  dim3 grid(nmat), block(256);
  hipLaunchKernelGGL(logm_kernel, grid, block, 0, stream, X, Y, cf);
}

// Round 4
// 192.016 us; speedup vs baseline: 2.0104x; 1.0168x over previous
//
#include <hip/hip_runtime.h>
#include <math.h>
#include <string.h>

#define CDIM 64
#define LDSW 72   // row stride in bf16 elems (144 B): b128 frag reads measured conflict-free
#define DEG  5    // Chebyshev tail on [1,7.5] ~5.6e-3; Paterson-Stockmeyer s=2 -> 3 matmuls

struct Coefs { float a[DEG + 1]; float cc; float inv_h; };

typedef __attribute__((ext_vector_type(8)))  short short8;    // 8 bf16 = 4 VGPRs (MFMA A/B frag)
typedef __attribute__((ext_vector_type(16))) float floatx16;  // MFMA C/D

// Row-major hi/lo store of one fp32 as two bf16 (truncation split).
// hi = top 16 bits of x (ds_write_b16_d16_hi pattern, no shift VALU);
// lo = bf16_trunc(x - hi), residual ~2^-16 |x|.
// Write pattern per instruction: half-wave writes 32 consecutive u16 of row q,
// other half row q+4 -> 32 disjoint banks, in-dword lane merge: 0 conflicts (measured R2).
__device__ __forceinline__ void st_hilo(unsigned short* __restrict__ Dh,
                                        unsigned short* __restrict__ Dl,
                                        int idx, float x) {
  const unsigned u = __builtin_bit_cast(unsigned, x);
  const float h = __builtin_bit_cast(float, u & 0xFFFF0000u);
  const float l = x - h;                       // exact
  const unsigned ul = __builtin_bit_cast(unsigned, l);
  Dh[idx] = (unsigned short)(u >> 16);
  Dl[idx] = (unsigned short)(ul >> 16);
}

struct Frags { short8 h[4]; short8 l[4]; };    // 4 K-slabs of hi+lo fragments

__device__ __forceinline__ void load_frags(const unsigned short* __restrict__ Ph,
                                           const unsigned short* __restrict__ Pl,
                                           int row, int ko, Frags* f) {
#pragma unroll
  for (int kk = 0; kk < 4; ++kk) {
    f->h[kk] = *(const short8*)(Ph + row * LDSW + kk * 16 + ko);
    f->l[kk] = *(const short8*)(Pl + row * LDSW + kk * 16 + ko);
  }
}

// 32x32 tile product with 3-MFMA compensated split, 3 independent acc chains.
__device__ __forceinline__ floatx16 mm_frags(const Frags& a, const Frags& b) {
  floatx16 c1, c2, c3;
#pragma unroll
  for (int i = 0; i < 16; ++i) { c1[i] = 0.0f; c2[i] = 0.0f; c3[i] = 0.0f; }
#pragma unroll
  for (int kk = 0; kk < 4; ++kk) {
    c1 = __builtin_amdgcn_mfma_f32_32x32x16_bf16(a.h[kk], b.h[kk], c1, 0, 0, 0);
    c2 = __builtin_amdgcn_mfma_f32_32x32x16_bf16(a.h[kk], b.l[kk], c2, 0, 0, 0);
    c3 = __builtin_amdgcn_mfma_f32_32x32x16_bf16(a.l[kk], b.h[kk], c3, 0, 0, 0);
  }
#pragma unroll
  for (int i = 0; i < 16; ++i) c1[i] += c2[i] + c3[i];
  return c1;
}

__global__ void __launch_bounds__(256, 2)
logm_kernel(const float* __restrict__ X, float* __restrict__ Y, Coefs cf) {
  // Buffers: A = M1 then Q1, B = Q0, C = M2.  6 x 9216 B = 55.3 KB -> 2 blocks/CU.
  __shared__ __align__(16) unsigned short Ah[CDIM * LDSW], Al[CDIM * LDSW];
  __shared__ __align__(16) unsigned short Bh[CDIM * LDSW], Bl[CDIM * LDSW];
  __shared__ __align__(16) unsigned short Ch[CDIM * LDSW], Cl[CDIM * LDSW];

  const int tid  = threadIdx.x;
  const int lane = tid & 63;
  const int w    = tid >> 6;
  const int m    = blockIdx.x;

  const float* __restrict__ Xm = X + (size_t)m * (CDIM * CDIM);
  float* __restrict__ Ym       = Y + (size_t)m * (CDIM * CDIM);

  const int R    = (w >> 1) * 32;
  const int Cc   = (w & 1) * 32;
  const int l31  = lane & 31;
  const int half = lane >> 5;
  const int arow = R + l31;
  const int brow = Cc + l31;
  const int ko   = half * 8;
  const int col  = Cc + l31;
  int rows[16];  // C/D layout: row = (r&3) + 8*(r>>2) + 4*half  [verified m74/m101]
#pragma unroll
  for (int r = 0; r < 16; ++r) rows[r] = R + (r & 3) + 8 * (r >> 2) + 4 * half;

  // ---- stage: load X once in C-layout (coalesced 2x128B per instr), keep rM1 in regs,
  //      write M1 -> A and Q0 = a4 I + a5 M1 -> B (row-major b16 hi/lo, conflict-free) ----
  float rM1[16];
#pragma unroll
  for (int r = 0; r < 16; ++r) {
    float x = Xm[rows[r] * CDIM + col];
    if (rows[r] == col) x -= cf.cc;
    const float t = x * cf.inv_h;
    rM1[r] = t;
    const int idx = rows[r] * LDSW + col;
    st_hilo(Ah, Al, idx, t);
    float q = cf.a[5] * t;
    if (rows[r] == col) q += cf.a[4];
    st_hilo(Bh, Bl, idx, q);
  }
  __syncthreads();

  // ---- mm1: M2 = M1*M1 -> C ----
  Frags fa, fb;
  load_frags(Ah, Al, arow, ko, &fa);
  if (R == Cc) fb = fa; else load_frags(Ah, Al, brow, ko, &fb);  // wave-uniform branch
  floatx16 accM2 = mm_frags(fa, fb);
#pragma unroll
  for (int r = 0; r < 16; ++r) st_hilo(Ch, Cl, rows[r] * LDSW + col, accM2[r]);
  __syncthreads();

  // ---- mm2: Q1 = Q0*M2 + (a2 I + a3 M1) -> A  (A's readers done at prev barrier) ----
  Frags fq, fm2;
  load_frags(Bh, Bl, arow, ko, &fq);     // A-operand Q0: true rows, no symmetry needed
  load_frags(Ch, Cl, brow, ko, &fm2);    // B-operand M2 via bitwise symmetry; cached for mm3
  floatx16 accQ = mm_frags(fq, fm2);
#pragma unroll
  for (int r = 0; r < 16; ++r) {
    float p = accQ[r] + cf.a[3] * rM1[r];
    if (rows[r] == col) p += cf.a[2];
    st_hilo(Ah, Al, rows[r] * LDSW + col, p);
  }
  __syncthreads();

  // ---- mm3: out = Q1*M2 + (a0 I + a1 M1) -> global (2x128B coalesced per instr) ----
  Frags fq1;
  load_frags(Ah, Al, arow, ko, &fq1);
  floatx16 accF = mm_frags(fq1, fm2);
#pragma unroll
  for (int r = 0; r < 16; ++r) {
    float p = accF[r] + cf.a[1] * rM1[r];
    if (rows[r] == col) p += cf.a[0];
    Ym[rows[r] * CDIM + col] = p;
  }
}

extern "C" void kernel_launch(void* const* d_in, const int* in_sizes, int n_in,
                              void* d_out, int out_size, void* d_ws, size_t ws_size,
                              hipStream_t stream) {
  const float* X = (const float*)d_in[0];
  float* Y = (float*)d_out;
  const int nmat = in_sizes[0] / (CDIM * CDIM);

  // Chebyshev coefficients of log on [lo,hi] -> monomial basis in t=(x-cc)/hh.
  // Analytic: log(cc+hh*t) = log(A) - 2*sum_k z^k/k T_k(t),  z=(-cc+sqrt(cc^2-hh^2))/hh
  Coefs cf;
  {
    const double lo = 1.0, hi = 7.5;
    const double cc = 0.5 * (lo + hi), hh = 0.5 * (hi - lo);
    const double s  = sqrt(cc * cc - hh * hh);
    const double z  = (-cc + s) / hh;
    const double A  = 0.5 * (cc + s);
    double cheb[DEG + 1];
    cheb[0] = log(A);
    double zp = 1.0;
    for (int k = 1; k <= DEG; ++k) { zp *= z; cheb[k] = -2.0 * zp / (double)k; }
    double mono[DEG + 1], Tprev[DEG + 1], Tcur[DEG + 1];
    memset(mono, 0, sizeof(mono));
    memset(Tprev, 0, sizeof(Tprev));
    memset(Tcur, 0, sizeof(Tcur));
    Tprev[0] = 1.0; mono[0] += cheb[0];
    Tcur[1]  = 1.0; mono[1] += cheb[1];
    for (int k = 2; k <= DEG; ++k) {
      double Tn[DEG + 1];
      memset(Tn, 0, sizeof(Tn));
      for (int j = 0; j <= k; ++j) {
        double v = -Tprev[j];
        if (j > 0) v += 2.0 * Tcur[j - 1];
        Tn[j] = v;
      }
      for (int j = 0; j <= k; ++j) mono[j] += cheb[k] * Tn[j];
      for (int j = 0; j <= DEG; ++j) { Tprev[j] = Tcur[j]; Tcur[j] = Tn[j]; }
    }
    for (int i = 0; i <= DEG; ++i) cf.a[i] = (float)mono[i];
    cf.cc = (float)cc; cf.inv_h = (float)(1.0 / hh);
  }

  dim3 grid(nmat), block(256);
  hipLaunchKernelGGL(logm_kernel, grid, block, 0, stream, X, Y, cf);
}